// Round 1
// baseline (214.312 us; speedup 1.0000x reference)
//
#include <hip/hip_runtime.h>
#include <hip/hip_bf16.h>

// Shapes fixed by the problem:
// B=4, S=1024, D=512, H=64, DK=8, FF=2048, NQ=8. Mtok = B*S = 4096.

typedef short short8 __attribute__((ext_vector_type(8)));
typedef float floatx4 __attribute__((ext_vector_type(4)));

#define BM 128
#define BN 128
#define BK 32

__device__ __forceinline__ unsigned short f2bf_bits(float f) {
  __hip_bfloat16 h = __float2bfloat16(f);
  return *reinterpret_cast<unsigned short*>(&h);
}

// ---------------------------------------------------------------------------
// C[M,N] = A[M,K] @ W[N,K]^T + bias[N]   (A,W bf16 row-major, C fp32)
// m97-style 128x128 tile, 4 waves, each wave 64x64 via 4x4 grid of 16x16x32
// MFMA. Early-returns (whole grid) when *skipgate == 1.0f.
// ---------------------------------------------------------------------------
__global__ __launch_bounds__(256) void gemm_bt_bias(
    const __hip_bfloat16* __restrict__ A,
    const __hip_bfloat16* __restrict__ W,
    const float* __restrict__ bias,
    float* __restrict__ C,
    int M, int N, int K,
    const float* __restrict__ skipgate)
{
  if (skipgate != nullptr && *skipgate == 1.0f) return;
  __shared__ __align__(16) __hip_bfloat16 As[BM][BK];
  __shared__ __align__(16) __hip_bfloat16 Bs[BN][BK];
  const int tid  = threadIdx.x;
  const int lane = tid & 63;
  const int wave = tid >> 6;
  const int wm = (wave >> 1) << 6;   // wave row offset in tile
  const int wn = (wave & 1) << 6;    // wave col offset in tile
  const long m0 = (long)blockIdx.x * BM;
  const long n0 = (long)blockIdx.y * BN;

  floatx4 acc[4][4];
#pragma unroll
  for (int i = 0; i < 4; ++i)
#pragma unroll
    for (int j = 0; j < 4; ++j)
      acc[i][j] = (floatx4){0.f, 0.f, 0.f, 0.f};

  const int ldr = tid >> 2;          // 0..63: row within 64-row half-tile
  const int ldc = (tid & 3) << 3;    // 0,8,16,24: bf16 col offset (16B chunk)
  const int mrow = lane & 15;        // MFMA fragment row/col
  const int koff = (lane >> 4) << 3; // MFMA fragment k offset

  for (int kt = 0; kt < K; kt += BK) {
    // global -> regs (A rows m0+ldr / m0+64+ldr, W rows n0+ldr / n0+64+ldr)
    uint4 av0 = *(const uint4*)(A + (m0 + ldr) * K + kt + ldc);
    uint4 av1 = *(const uint4*)(A + (m0 + 64 + ldr) * K + kt + ldc);
    uint4 bv0 = *(const uint4*)(W + (n0 + ldr) * K + kt + ldc);
    uint4 bv1 = *(const uint4*)(W + (n0 + 64 + ldr) * K + kt + ldc);
    __syncthreads();   // previous iteration's fragment reads done
    *(uint4*)(&As[ldr][ldc])      = av0;
    *(uint4*)(&As[64 + ldr][ldc]) = av1;
    *(uint4*)(&Bs[ldr][ldc])      = bv0;
    *(uint4*)(&Bs[64 + ldr][ldc]) = bv1;
    __syncthreads();   // stores visible

    short8 afrag[4], bfrag[4];
#pragma unroll
    for (int i = 0; i < 4; ++i)
      afrag[i] = *(const short8*)(&As[wm + i * 16 + mrow][koff]);
#pragma unroll
    for (int j = 0; j < 4; ++j)
      bfrag[j] = *(const short8*)(&Bs[wn + j * 16 + mrow][koff]);
#pragma unroll
    for (int i = 0; i < 4; ++i)
#pragma unroll
      for (int j = 0; j < 4; ++j)
        acc[i][j] = __builtin_amdgcn_mfma_f32_16x16x32_bf16(
            afrag[i], bfrag[j], acc[i][j], 0, 0, 0);
  }

  // epilogue: D row=(lane>>4)*4+reg, col=lane&15 (verified m89/m91 layout)
  const int col_l = lane & 15;
  const int row_l = (lane >> 4) << 2;
#pragma unroll
  for (int j = 0; j < 4; ++j) {
    const long col = n0 + wn + j * 16 + col_l;
    const float bv = (bias != nullptr) ? bias[col] : 0.0f;
#pragma unroll
    for (int i = 0; i < 4; ++i) {
#pragma unroll
      for (int r = 0; r < 4; ++r) {
        const long row = m0 + wm + i * 16 + row_l + r;
        C[row * N + col] = acc[i][j][r] + bv;
      }
    }
  }
}

// ---------------------------------------------------------------------------
// fp32 -> bf16 conversion for up to 4 arrays (all n divisible by 4)
// ---------------------------------------------------------------------------
__device__ __forceinline__ void cvt_one(const float* s, __hip_bfloat16* d, int n,
                                        long tid, long stride) {
  if (s == nullptr || n <= 0) return;
  const int n4 = n >> 2;
  for (long i = tid; i < n4; i += stride) {
    float4 v = ((const float4*)s)[i];
    ushort4 u;
    u.x = f2bf_bits(v.x); u.y = f2bf_bits(v.y);
    u.z = f2bf_bits(v.z); u.w = f2bf_bits(v.w);
    ((ushort4*)d)[i] = u;
  }
}

__global__ __launch_bounds__(256) void cvt_bf16_4(
    const float* s0, __hip_bfloat16* d0, int n0,
    const float* s1, __hip_bfloat16* d1, int n1,
    const float* s2, __hip_bfloat16* d2, int n2,
    const float* s3, __hip_bfloat16* d3, int n3,
    const float* skipgate)
{
  if (skipgate != nullptr && *skipgate == 1.0f) return;
  const long stride = (long)gridDim.x * blockDim.x;
  const long tid = (long)blockIdx.x * blockDim.x + threadIdx.x;
  cvt_one(s0, d0, n0, tid, stride);
  cvt_one(s1, d1, n1, tid, stride);
  cvt_one(s2, d2, n2, tid, stride);
  cvt_one(s3, d3, n3, tid, stride);
}

// ---------------------------------------------------------------------------
// quantum attention transform + gate mix, one thread per (b,s,h) group of 8.
// o[0] = c1*..*c7 ; o[j>=1] = c0*..*cj ; c_i = cos(q_i + theta_i).
// Writes mix = g*quantum + (1-g)*classical as bf16 (input to Wo GEMM).
// ---------------------------------------------------------------------------
__global__ __launch_bounds__(256) void quantum_mix(
    const float* __restrict__ Q, const float* __restrict__ theta,
    const float* __restrict__ gate, const float* __restrict__ cls,
    __hip_bfloat16* __restrict__ mix, int ngroups)
{
  const int g = blockIdx.x * blockDim.x + threadIdx.x;
  if (g >= ngroups) return;
  const float4* qp = (const float4*)(Q + (long)g * 8);
  float4 q0 = qp[0], q1 = qp[1];
  float c[8];
  c[0] = __cosf(q0.x + theta[0]);
  c[1] = __cosf(q0.y + theta[1]);
  c[2] = __cosf(q0.z + theta[2]);
  c[3] = __cosf(q0.w + theta[3]);
  c[4] = __cosf(q1.x + theta[4]);
  c[5] = __cosf(q1.y + theta[5]);
  c[6] = __cosf(q1.z + theta[6]);
  c[7] = __cosf(q1.w + theta[7]);
  float o[8];
  float p = c[1];
#pragma unroll
  for (int i = 2; i < 8; ++i) p *= c[i];
  o[0] = p;
  float cp = c[0];
#pragma unroll
  for (int i = 1; i < 8; ++i) { cp *= c[i]; o[i] = cp; }
  const float gv = *gate;
  if (gv != 1.0f) {
    const float* cr = cls + (long)g * 8;
#pragma unroll
    for (int i = 0; i < 8; ++i) o[i] = gv * o[i] + (1.0f - gv) * cr[i];
  }
  union { unsigned short u16[8]; uint4 v; } pk;
#pragma unroll
  for (int i = 0; i < 8; ++i) pk.u16[i] = f2bf_bits(o[i]);
  *(uint4*)(mix + (long)g * 8) = pk.v;
}

// ---------------------------------------------------------------------------
// out = LayerNorm(a + mix(b, b_alt; gate)) * w + bias, row length 512.
// Optionally writes qm[row, 0:8] = cos(out)*cos(phi) (FFN quantum input).
// ---------------------------------------------------------------------------
__global__ __launch_bounds__(256) void add_ln(
    const float* __restrict__ a, const float* __restrict__ b,
    const float* __restrict__ b_alt, const float* __restrict__ gate,
    const float* __restrict__ w, const float* __restrict__ bias,
    float* __restrict__ out, const float* __restrict__ phi,
    float* __restrict__ qm)
{
  const int row = blockIdx.x;
  const int tid = threadIdx.x;
  const long base = (long)row * 512;
  const int c0 = tid * 2;
  float2 av = *(const float2*)(a + base + c0);
  float2 bv = *(const float2*)(b + base + c0);
  float s0, s1;
  const float gv = (gate != nullptr) ? *gate : 1.0f;
  if (gate != nullptr && gv != 1.0f) {
    float2 cv = *(const float2*)(b_alt + base + c0);
    s0 = av.x + gv * bv.x + (1.0f - gv) * cv.x;
    s1 = av.y + gv * bv.y + (1.0f - gv) * cv.y;
  } else {
    s0 = av.x + bv.x;
    s1 = av.y + bv.y;
  }
  float sum = s0 + s1;
  float ssq = s0 * s0 + s1 * s1;
#pragma unroll
  for (int off = 32; off > 0; off >>= 1) {
    sum += __shfl_down(sum, off);
    ssq += __shfl_down(ssq, off);
  }
  __shared__ float red[8];
  const int wv = tid >> 6, ln = tid & 63;
  if (ln == 0) { red[wv] = sum; red[4 + wv] = ssq; }
  __syncthreads();
  if (tid == 0) {
    float ts = red[0] + red[1] + red[2] + red[3];
    float tq = red[4] + red[5] + red[6] + red[7];
    float mean = ts * (1.0f / 512.0f);
    float var = tq * (1.0f / 512.0f) - mean * mean;
    red[0] = mean;
    red[1] = rsqrtf(fmaxf(var, 0.0f) + 1e-5f);
  }
  __syncthreads();
  const float mean = red[0], rstd = red[1];
  const float o0 = (s0 - mean) * rstd * w[c0] + bias[c0];
  const float o1 = (s1 - mean) * rstd * w[c0 + 1] + bias[c0 + 1];
  float2 ov; ov.x = o0; ov.y = o1;
  *(float2*)(out + base + c0) = ov;
  if (qm != nullptr && c0 < 8) {
    qm[(long)row * 8 + c0]     = __cosf(o0) * __cosf(phi[c0]);
    qm[(long)row * 8 + c0 + 1] = __cosf(o1) * __cosf(phi[c0 + 1]);
  }
}

// ---------------------------------------------------------------------------
// h[m,n] = relu(sum_{k<8} in[m,k]*W1[n,k] + b1[n]) -> bf16. One block per m.
// ---------------------------------------------------------------------------
__global__ __launch_bounds__(256) void ffn_h(
    const float* __restrict__ in, int in_stride,
    const float* __restrict__ W1, const float* __restrict__ b1,
    __hip_bfloat16* __restrict__ h, const float* __restrict__ skipgate)
{
  if (skipgate != nullptr && *skipgate == 1.0f) return;
  const int m = blockIdx.x;
  const float* xr = in + (long)m * in_stride;
  float xv[8];
#pragma unroll
  for (int i = 0; i < 8; ++i) xv[i] = xr[i];
  for (int n = threadIdx.x; n < 2048; n += 256) {
    const float4* wr = (const float4*)(W1 + n * 8);
    float4 w0 = wr[0], w1 = wr[1];
    float acc = b1[n];
    acc += xv[0] * w0.x + xv[1] * w0.y + xv[2] * w0.z + xv[3] * w0.w;
    acc += xv[4] * w1.x + xv[5] * w1.y + xv[6] * w1.z + xv[7] * w1.w;
    h[(long)m * 2048 + n] = __float2bfloat16(fmaxf(acc, 0.0f));
  }
}

// ---------------------------------------------------------------------------
// Classical softmax attention fallback (only runs when gate_attn != 1).
// One thread per (b,h,s) query, online softmax over 1024 keys, DK=8.
// ---------------------------------------------------------------------------
__global__ __launch_bounds__(256) void attn_classical(
    const float* __restrict__ Q, const float* __restrict__ Kb,
    const float* __restrict__ Vb, float* __restrict__ cls,
    const float* __restrict__ skipgate)
{
  if (*skipgate == 1.0f) return;
  const int idx = blockIdx.x * blockDim.x + threadIdx.x;
  if (idx >= 4 * 64 * 1024) return;
  const int s = idx & 1023;
  const int h = (idx >> 10) & 63;
  const int b = idx >> 16;
  const long qoff = ((long)(b * 1024 + s)) * 512 + h * 8;
  float q[8];
#pragma unroll
  for (int i = 0; i < 8; ++i) q[i] = Q[qoff + i] * 0.35355339059327373f;
  float m = -INFINITY, l = 0.0f, acc[8];
#pragma unroll
  for (int i = 0; i < 8; ++i) acc[i] = 0.0f;
  for (int t = 0; t < 1024; ++t) {
    const long koff = ((long)(b * 1024 + t)) * 512 + h * 8;
    const float* kr = Kb + koff;
    const float* vr = Vb + koff;
    float sc = 0.0f;
#pragma unroll
    for (int i = 0; i < 8; ++i) sc += q[i] * kr[i];
    float nm = fmaxf(m, sc);
    float corr = __expf(m - nm);
    float p = __expf(sc - nm);
    l = l * corr + p;
#pragma unroll
    for (int i = 0; i < 8; ++i) acc[i] = acc[i] * corr + p * vr[i];
    m = nm;
  }
  const float inv = 1.0f / l;
#pragma unroll
  for (int i = 0; i < 8; ++i) cls[qoff + i] = acc[i] * inv;
}

// ---------------------------------------------------------------------------
extern "C" void kernel_launch(void* const* d_in, const int* in_sizes, int n_in,
                              void* d_out, int out_size, void* d_ws, size_t ws_size,
                              hipStream_t stream) {
  const float* x     = (const float*)d_in[0];
  const float* Wq    = (const float*)d_in[1];
  const float* bq    = (const float*)d_in[2];
  const float* Wk    = (const float*)d_in[3];
  const float* bk    = (const float*)d_in[4];
  const float* Wv    = (const float*)d_in[5];
  const float* bv    = (const float*)d_in[6];
  const float* theta = (const float*)d_in[7];
  const float* gateA = (const float*)d_in[8];
  const float* Wo    = (const float*)d_in[9];
  const float* bo    = (const float*)d_in[10];
  const float* ln1w  = (const float*)d_in[11];
  const float* ln1b  = (const float*)d_in[12];
  const float* W1    = (const float*)d_in[13];
  const float* b1    = (const float*)d_in[14];
  const float* W2    = (const float*)d_in[15];
  const float* b2    = (const float*)d_in[16];
  const float* phi   = (const float*)d_in[17];
  const float* gateF = (const float*)d_in[18];
  const float* ln2w  = (const float*)d_in[19];
  const float* ln2b  = (const float*)d_in[20];
  float* out = (float*)d_out;

  const int Mtok = 4096, Dm = 512, FFn = 2048;
  const size_t MB = 1024 * 1024;
  char* wsb = (char*)d_ws;
  // live (gate==1) buffers: total extent 52 MB
  __hip_bfloat16* x_bf   = (__hip_bfloat16*)(wsb + 0 * MB);            // 4 MB
  __hip_bfloat16* Wq_bf  = (__hip_bfloat16*)(wsb + 4 * MB);            // 0.5 MB
  __hip_bfloat16* Wo_bf  = (__hip_bfloat16*)(wsb + 4 * MB + 512 * 1024);
  __hip_bfloat16* W2_bf  = (__hip_bfloat16*)(wsb + 5 * MB);            // 2 MB
  float*          Qb     = (float*)(wsb + 7 * MB);                     // 8 MB
  __hip_bfloat16* mix_bf = (__hip_bfloat16*)(wsb + 15 * MB);           // 4 MB
  float*          attn   = (float*)(wsb + 19 * MB);                    // 8 MB
  float*          x1     = (float*)(wsb + 27 * MB);                    // 8 MB
  float*          qmb    = (float*)(wsb + 35 * MB);                    // 128 KB
  __hip_bfloat16* hq_bf  = (__hip_bfloat16*)(wsb + 36 * MB);           // 16 MB
  float*          Fb     = Qb;  // Q dead after quantum_mix; reuse for FFN out
  // conditional (gate != 1) buffers — never touched when gates == 1
  __hip_bfloat16* Wk_bf  = (__hip_bfloat16*)(wsb + 52 * MB);
  __hip_bfloat16* Wv_bf  = (__hip_bfloat16*)(wsb + 52 * MB + 512 * 1024);
  float*          Kb2    = (float*)(wsb + 53 * MB);
  float*          Vb2    = (float*)(wsb + 61 * MB);
  float*          clsb   = (float*)(wsb + 69 * MB);
  __hip_bfloat16* hc_bf  = (__hip_bfloat16*)(wsb + 77 * MB);
  float*          Fc     = (float*)(wsb + 93 * MB);

  // 1. bf16 conversions (always-live operands)
  cvt_bf16_4<<<1024, 256, 0, stream>>>(
      x, x_bf, Mtok * Dm, Wq, Wq_bf, Dm * Dm,
      Wo, Wo_bf, Dm * Dm, W2, W2_bf, Dm * FFn, nullptr);
  // 2. conditional conversions (Wk, Wv)
  cvt_bf16_4<<<512, 256, 0, stream>>>(
      Wk, Wk_bf, Dm * Dm, Wv, Wv_bf, Dm * Dm,
      nullptr, nullptr, 0, nullptr, nullptr, 0, gateA);
  // 3. Q = x @ Wq^T + bq
  gemm_bt_bias<<<dim3(32, 4), 256, 0, stream>>>(
      x_bf, Wq_bf, bq, Qb, Mtok, Dm, Dm, nullptr);
  // 4/5. K, V projections (conditional)
  gemm_bt_bias<<<dim3(32, 4), 256, 0, stream>>>(
      x_bf, Wk_bf, bk, Kb2, Mtok, Dm, Dm, gateA);
  gemm_bt_bias<<<dim3(32, 4), 256, 0, stream>>>(
      x_bf, Wv_bf, bv, Vb2, Mtok, Dm, Dm, gateA);
  // 6. classical softmax attention (conditional)
  attn_classical<<<1024, 256, 0, stream>>>(Qb, Kb2, Vb2, clsb, gateA);
  // 7. quantum transform + gate mix -> bf16
  quantum_mix<<<1024, 256, 0, stream>>>(Qb, theta, gateA, clsb, mix_bf,
                                        Mtok * 64);
  // 8. attn_out = mix @ Wo^T + bo
  gemm_bt_bias<<<dim3(32, 4), 256, 0, stream>>>(
      mix_bf, Wo_bf, bo, attn, Mtok, Dm, Dm, nullptr);
  // 9. x1 = LN(x + attn_out); qm = cos(x1[:, :8]) * cos(phi)
  add_ln<<<4096, 256, 0, stream>>>(x, attn, nullptr, nullptr,
                                   ln1w, ln1b, x1, phi, qmb);
  // 10. hq = relu(qm @ W1^T + b1) (bf16)
  ffn_h<<<4096, 256, 0, stream>>>(qmb, 8, W1, b1, hq_bf, nullptr);
  // 11. hc = relu(x1[:, :8] @ W1^T + b1) (conditional)
  ffn_h<<<4096, 256, 0, stream>>>(x1, 512, W1, b1, hc_bf, gateF);
  // 12. F = hq @ W2^T + b2
  gemm_bt_bias<<<dim3(32, 4), 256, 0, stream>>>(
      hq_bf, W2_bf, b2, Fb, Mtok, Dm, FFn, nullptr);
  // 13. Fc = hc @ W2^T + b2 (conditional)
  gemm_bt_bias<<<dim3(32, 4), 256, 0, stream>>>(
      hc_bf, W2_bf, b2, Fc, Mtok, Dm, FFn, gateF);
  // 14. out = LN(x1 + gF*F + (1-gF)*Fc)
  add_ln<<<4096, 256, 0, stream>>>(x1, Fb, Fc, gateF,
                                   ln2w, ln2b, out, nullptr, nullptr);
}

// Round 2
// 182.557 us; speedup vs baseline: 1.1739x; 1.1739x over previous
//
#include <hip/hip_runtime.h>
#include <hip/hip_bf16.h>

// Shapes fixed by the problem:
// B=4, S=1024, D=512, H=64, DK=8, FF=2048, NQ=8. Mtok = B*S = 4096.

typedef short short8 __attribute__((ext_vector_type(8)));
typedef float floatx4 __attribute__((ext_vector_type(4)));

__device__ __forceinline__ unsigned short f2bf_bits(float f) {
  __hip_bfloat16 h = __float2bfloat16(f);
  return *reinterpret_cast<unsigned short*>(&h);
}

#define GLOBAL_LOAD_LDS16(g, l)                                               \
  __builtin_amdgcn_global_load_lds(                                           \
      (const __attribute__((address_space(1))) void*)(g),                     \
      (__attribute__((address_space(3))) void*)(l), 16, 0, 0)

// ---------------------------------------------------------------------------
// C[M,N] = A[M,K] @ W[N,K]^T + bias[N]   (A,W bf16 row-major, C fp32)
// 64x64 tile, BK=64, 4 waves (each 32x32 via 2x2 of 16x16x32 MFMA).
// global_load_lds width-16 staging with XOR chunk swizzle:
//   LDS physical 16B-chunk p of row r holds logical k-chunk (p ^ (r&7)).
// Early-returns (whole grid) when *skipgate == 1.0f.
// Grid: (M/64, N/64). M,N,K all divisible by 64.
// ---------------------------------------------------------------------------
__global__ __launch_bounds__(256) void gemm_bt_bias(
    const __hip_bfloat16* __restrict__ A,
    const __hip_bfloat16* __restrict__ W,
    const float* __restrict__ bias,
    float* __restrict__ C,
    int M, int N, int K,
    const float* __restrict__ skipgate)
{
  if (skipgate != nullptr && *skipgate == 1.0f) return;
  __shared__ __align__(16) __hip_bfloat16 As[64 * 64];
  __shared__ __align__(16) __hip_bfloat16 Bs[64 * 64];
  const int tid  = threadIdx.x;
  const int lane = tid & 63;
  const int wave = tid >> 6;
  const int wm = (wave >> 1) << 5;   // 0 or 32: wave row offset in tile
  const int wn = (wave & 1) << 5;    // 0 or 32: wave col offset in tile
  const long m0 = (long)blockIdx.x * 64;
  const long n0 = (long)blockIdx.y * 64;

  floatx4 acc[2][2];
#pragma unroll
  for (int i = 0; i < 2; ++i)
#pragma unroll
    for (int j = 0; j < 2; ++j)
      acc[i][j] = (floatx4){0.f, 0.f, 0.f, 0.f};

  // staging geometry: each global_load_lds stages 1 KB = 8 rows x 8 chunks.
  // lane i -> phys (row = rb*8 + i/8, chunk = i&7); global logical chunk =
  // (i&7) ^ (row&7).
  const int srow = lane >> 3;        // row within 8-row block
  const int schunk = lane & 7;       // physical chunk
  // fragment geometry
  const int frow = lane & 15;
  const int fk = lane >> 4;          // 0..3

  for (int kt = 0; kt < K; kt += 64) {
    __syncthreads();   // previous tile's fragment reads done
#pragma unroll
    for (int jj = 0; jj < 2; ++jj) {
      const int rb = wave * 2 + jj;          // 8-row block 0..7
      const int row = rb * 8 + srow;
      const int gc = ((schunk ^ (row & 7)) << 3);
      GLOBAL_LOAD_LDS16(A + (m0 + row) * K + kt + gc, As + rb * 512);
      GLOBAL_LOAD_LDS16(W + (n0 + row) * K + kt + gc, Bs + rb * 512);
    }
    __syncthreads();   // vmcnt drained by compiler before barrier

    short8 af[2][2], bfr[2][2];    // [ks][i]
#pragma unroll
    for (int ks = 0; ks < 2; ++ks)
#pragma unroll
      for (int i = 0; i < 2; ++i) {
        const int ar = wm + i * 16 + frow;
        const int ac = (ks * 4 + fk) ^ (ar & 7);
        af[ks][i] = *(const short8*)(As + ar * 64 + ac * 8);
        const int br = wn + i * 16 + frow;
        const int bc = (ks * 4 + fk) ^ (br & 7);
        bfr[ks][i] = *(const short8*)(Bs + br * 64 + bc * 8);
      }
#pragma unroll
    for (int ks = 0; ks < 2; ++ks)
#pragma unroll
      for (int i = 0; i < 2; ++i)
#pragma unroll
        for (int j = 0; j < 2; ++j)
          acc[i][j] = __builtin_amdgcn_mfma_f32_16x16x32_bf16(
              af[ks][i], bfr[ks][j], acc[i][j], 0, 0, 0);
  }

  // epilogue: D row=(lane>>4)*4+reg, col=lane&15 (verified m89/m91 layout)
  const int col_l = lane & 15;
  const int row_l = (lane >> 4) << 2;
#pragma unroll
  for (int j = 0; j < 2; ++j) {
    const long col = n0 + wn + j * 16 + col_l;
    const float bv = (bias != nullptr) ? bias[col] : 0.0f;
#pragma unroll
    for (int i = 0; i < 2; ++i) {
#pragma unroll
      for (int r = 0; r < 4; ++r) {
        const long row = m0 + wm + i * 16 + row_l + r;
        C[row * N + col] = acc[i][j][r] + bv;
      }
    }
  }
}

// ---------------------------------------------------------------------------
// fp32 -> bf16 conversion for up to 4 arrays (all n divisible by 4)
// ---------------------------------------------------------------------------
__device__ __forceinline__ void cvt_one(const float* s, __hip_bfloat16* d, int n,
                                        long tid, long stride) {
  if (s == nullptr || n <= 0) return;
  const int n4 = n >> 2;
  for (long i = tid; i < n4; i += stride) {
    float4 v = ((const float4*)s)[i];
    ushort4 u;
    u.x = f2bf_bits(v.x); u.y = f2bf_bits(v.y);
    u.z = f2bf_bits(v.z); u.w = f2bf_bits(v.w);
    ((ushort4*)d)[i] = u;
  }
}

__global__ __launch_bounds__(256) void cvt_bf16_4(
    const float* s0, __hip_bfloat16* d0, int n0,
    const float* s1, __hip_bfloat16* d1, int n1,
    const float* s2, __hip_bfloat16* d2, int n2,
    const float* s3, __hip_bfloat16* d3, int n3,
    const float* skipgate)
{
  if (skipgate != nullptr && *skipgate == 1.0f) return;
  const long stride = (long)gridDim.x * blockDim.x;
  const long tid = (long)blockIdx.x * blockDim.x + threadIdx.x;
  cvt_one(s0, d0, n0, tid, stride);
  cvt_one(s1, d1, n1, tid, stride);
  cvt_one(s2, d2, n2, tid, stride);
  cvt_one(s3, d3, n3, tid, stride);
}

// ---------------------------------------------------------------------------
// quantum attention transform + gate mix, one thread per (b,s,h) group of 8.
// o[0] = c1*..*c7 ; o[j>=1] = c0*..*cj ; c_i = cos(q_i + theta_i).
// Writes mix = g*quantum + (1-g)*classical as bf16 (input to Wo GEMM).
// ---------------------------------------------------------------------------
__global__ __launch_bounds__(256) void quantum_mix(
    const float* __restrict__ Q, const float* __restrict__ theta,
    const float* __restrict__ gate, const float* __restrict__ cls,
    __hip_bfloat16* __restrict__ mix, int ngroups)
{
  const int g = blockIdx.x * blockDim.x + threadIdx.x;
  if (g >= ngroups) return;
  const float4* qp = (const float4*)(Q + (long)g * 8);
  float4 q0 = qp[0], q1 = qp[1];
  float c[8];
  c[0] = __cosf(q0.x + theta[0]);
  c[1] = __cosf(q0.y + theta[1]);
  c[2] = __cosf(q0.z + theta[2]);
  c[3] = __cosf(q0.w + theta[3]);
  c[4] = __cosf(q1.x + theta[4]);
  c[5] = __cosf(q1.y + theta[5]);
  c[6] = __cosf(q1.z + theta[6]);
  c[7] = __cosf(q1.w + theta[7]);
  float o[8];
  float p = c[1];
#pragma unroll
  for (int i = 2; i < 8; ++i) p *= c[i];
  o[0] = p;
  float cp = c[0];
#pragma unroll
  for (int i = 1; i < 8; ++i) { cp *= c[i]; o[i] = cp; }
  const float gv = *gate;
  if (gv != 1.0f) {
    const float* cr = cls + (long)g * 8;
#pragma unroll
    for (int i = 0; i < 8; ++i) o[i] = gv * o[i] + (1.0f - gv) * cr[i];
  }
  union { unsigned short u16[8]; uint4 v; } pk;
#pragma unroll
  for (int i = 0; i < 8; ++i) pk.u16[i] = f2bf_bits(o[i]);
  *(uint4*)(mix + (long)g * 8) = pk.v;
}

// ---------------------------------------------------------------------------
// out = LayerNorm(a + mix(b, b_alt; gate)) * w + bias, row length 512.
// Optionally writes qm[row, 0:8] = cos(out)*cos(phi) (FFN quantum input).
// ---------------------------------------------------------------------------
__global__ __launch_bounds__(256) void add_ln(
    const float* __restrict__ a, const float* __restrict__ b,
    const float* __restrict__ b_alt, const float* __restrict__ gate,
    const float* __restrict__ w, const float* __restrict__ bias,
    float* __restrict__ out, const float* __restrict__ phi,
    float* __restrict__ qm)
{
  const int row = blockIdx.x;
  const int tid = threadIdx.x;
  const long base = (long)row * 512;
  const int c0 = tid * 2;
  float2 av = *(const float2*)(a + base + c0);
  float2 bv = *(const float2*)(b + base + c0);
  float s0, s1;
  const float gv = (gate != nullptr) ? *gate : 1.0f;
  if (gate != nullptr && gv != 1.0f) {
    float2 cv = *(const float2*)(b_alt + base + c0);
    s0 = av.x + gv * bv.x + (1.0f - gv) * cv.x;
    s1 = av.y + gv * bv.y + (1.0f - gv) * cv.y;
  } else {
    s0 = av.x + bv.x;
    s1 = av.y + bv.y;
  }
  float sum = s0 + s1;
  float ssq = s0 * s0 + s1 * s1;
#pragma unroll
  for (int off = 32; off > 0; off >>= 1) {
    sum += __shfl_down(sum, off);
    ssq += __shfl_down(ssq, off);
  }
  __shared__ float red[8];
  const int wv = tid >> 6, ln = tid & 63;
  if (ln == 0) { red[wv] = sum; red[4 + wv] = ssq; }
  __syncthreads();
  if (tid == 0) {
    float ts = red[0] + red[1] + red[2] + red[3];
    float tq = red[4] + red[5] + red[6] + red[7];
    float mean = ts * (1.0f / 512.0f);
    float var = tq * (1.0f / 512.0f) - mean * mean;
    red[0] = mean;
    red[1] = rsqrtf(fmaxf(var, 0.0f) + 1e-5f);
  }
  __syncthreads();
  const float mean = red[0], rstd = red[1];
  const float o0 = (s0 - mean) * rstd * w[c0] + bias[c0];
  const float o1 = (s1 - mean) * rstd * w[c0 + 1] + bias[c0 + 1];
  float2 ov; ov.x = o0; ov.y = o1;
  *(float2*)(out + base + c0) = ov;
  if (qm != nullptr && c0 < 8) {
    qm[(long)row * 8 + c0]     = __cosf(o0) * __cosf(phi[c0]);
    qm[(long)row * 8 + c0 + 1] = __cosf(o1) * __cosf(phi[c0 + 1]);
  }
}

// ---------------------------------------------------------------------------
// h[m,n] = relu(sum_{k<8} in[m,k]*W1[n,k] + b1[n]) -> bf16. One block per m.
// ---------------------------------------------------------------------------
__global__ __launch_bounds__(256) void ffn_h(
    const float* __restrict__ in, int in_stride,
    const float* __restrict__ W1, const float* __restrict__ b1,
    __hip_bfloat16* __restrict__ h, const float* __restrict__ skipgate)
{
  if (skipgate != nullptr && *skipgate == 1.0f) return;
  const int m = blockIdx.x;
  const float* xr = in + (long)m * in_stride;
  float xv[8];
#pragma unroll
  for (int i = 0; i < 8; ++i) xv[i] = xr[i];
  for (int n = threadIdx.x; n < 2048; n += 256) {
    const float4* wr = (const float4*)(W1 + n * 8);
    float4 w0 = wr[0], w1 = wr[1];
    float acc = b1[n];
    acc += xv[0] * w0.x + xv[1] * w0.y + xv[2] * w0.z + xv[3] * w0.w;
    acc += xv[4] * w1.x + xv[5] * w1.y + xv[6] * w1.z + xv[7] * w1.w;
    h[(long)m * 2048 + n] = __float2bfloat16(fmaxf(acc, 0.0f));
  }
}

// ---------------------------------------------------------------------------
// Classical softmax attention fallback (only runs when gate_attn != 1).
// One thread per (b,h,s) query, online softmax over 1024 keys, DK=8.
// ---------------------------------------------------------------------------
__global__ __launch_bounds__(256) void attn_classical(
    const float* __restrict__ Q, const float* __restrict__ Kb,
    const float* __restrict__ Vb, float* __restrict__ cls,
    const float* __restrict__ skipgate)
{
  if (*skipgate == 1.0f) return;
  const int idx = blockIdx.x * blockDim.x + threadIdx.x;
  if (idx >= 4 * 64 * 1024) return;
  const int s = idx & 1023;
  const int h = (idx >> 10) & 63;
  const int b = idx >> 16;
  const long qoff = ((long)(b * 1024 + s)) * 512 + h * 8;
  float q[8];
#pragma unroll
  for (int i = 0; i < 8; ++i) q[i] = Q[qoff + i] * 0.35355339059327373f;
  float m = -INFINITY, l = 0.0f, acc[8];
#pragma unroll
  for (int i = 0; i < 8; ++i) acc[i] = 0.0f;
  for (int t = 0; t < 1024; ++t) {
    const long koff = ((long)(b * 1024 + t)) * 512 + h * 8;
    const float* kr = Kb + koff;
    const float* vr = Vb + koff;
    float sc = 0.0f;
#pragma unroll
    for (int i = 0; i < 8; ++i) sc += q[i] * kr[i];
    float nm = fmaxf(m, sc);
    float corr = __expf(m - nm);
    float p = __expf(sc - nm);
    l = l * corr + p;
#pragma unroll
    for (int i = 0; i < 8; ++i) acc[i] = acc[i] * corr + p * vr[i];
    m = nm;
  }
  const float inv = 1.0f / l;
#pragma unroll
  for (int i = 0; i < 8; ++i) cls[qoff + i] = acc[i] * inv;
}

// ---------------------------------------------------------------------------
extern "C" void kernel_launch(void* const* d_in, const int* in_sizes, int n_in,
                              void* d_out, int out_size, void* d_ws, size_t ws_size,
                              hipStream_t stream) {
  const float* x     = (const float*)d_in[0];
  const float* Wq    = (const float*)d_in[1];
  const float* bq    = (const float*)d_in[2];
  const float* Wk    = (const float*)d_in[3];
  const float* bk    = (const float*)d_in[4];
  const float* Wv    = (const float*)d_in[5];
  const float* bv    = (const float*)d_in[6];
  const float* theta = (const float*)d_in[7];
  const float* gateA = (const float*)d_in[8];
  const float* Wo    = (const float*)d_in[9];
  const float* bo    = (const float*)d_in[10];
  const float* ln1w  = (const float*)d_in[11];
  const float* ln1b  = (const float*)d_in[12];
  const float* W1    = (const float*)d_in[13];
  const float* b1    = (const float*)d_in[14];
  const float* W2    = (const float*)d_in[15];
  const float* b2    = (const float*)d_in[16];
  const float* phi   = (const float*)d_in[17];
  const float* gateF = (const float*)d_in[18];
  const float* ln2w  = (const float*)d_in[19];
  const float* ln2b  = (const float*)d_in[20];
  float* out = (float*)d_out;

  const int Mtok = 4096, Dm = 512, FFn = 2048;
  const size_t MB = 1024 * 1024;
  char* wsb = (char*)d_ws;
  // live (gate==1) buffers: total extent 52 MB
  __hip_bfloat16* x_bf   = (__hip_bfloat16*)(wsb + 0 * MB);            // 4 MB
  __hip_bfloat16* Wq_bf  = (__hip_bfloat16*)(wsb + 4 * MB);            // 0.5 MB
  __hip_bfloat16* Wo_bf  = (__hip_bfloat16*)(wsb + 4 * MB + 512 * 1024);
  __hip_bfloat16* W2_bf  = (__hip_bfloat16*)(wsb + 5 * MB);            // 2 MB
  float*          Qb     = (float*)(wsb + 7 * MB);                     // 8 MB
  __hip_bfloat16* mix_bf = (__hip_bfloat16*)(wsb + 15 * MB);           // 4 MB
  float*          attn   = (float*)(wsb + 19 * MB);                    // 8 MB
  float*          x1     = (float*)(wsb + 27 * MB);                    // 8 MB
  float*          qmb    = (float*)(wsb + 35 * MB);                    // 128 KB
  __hip_bfloat16* hq_bf  = (__hip_bfloat16*)(wsb + 36 * MB);           // 16 MB
  float*          Fb     = Qb;  // Q dead after quantum_mix; reuse for FFN out
  // conditional (gate != 1) buffers — never touched when gates == 1
  __hip_bfloat16* Wk_bf  = (__hip_bfloat16*)(wsb + 52 * MB);
  __hip_bfloat16* Wv_bf  = (__hip_bfloat16*)(wsb + 52 * MB + 512 * 1024);
  float*          Kb2    = (float*)(wsb + 53 * MB);
  float*          Vb2    = (float*)(wsb + 61 * MB);
  float*          clsb   = (float*)(wsb + 69 * MB);
  __hip_bfloat16* hc_bf  = (__hip_bfloat16*)(wsb + 77 * MB);
  float*          Fc     = (float*)(wsb + 93 * MB);

  // 1. bf16 conversions (always-live operands)
  cvt_bf16_4<<<1024, 256, 0, stream>>>(
      x, x_bf, Mtok * Dm, Wq, Wq_bf, Dm * Dm,
      Wo, Wo_bf, Dm * Dm, W2, W2_bf, Dm * FFn, nullptr);
  // 2. conditional conversions (Wk, Wv)
  cvt_bf16_4<<<512, 256, 0, stream>>>(
      Wk, Wk_bf, Dm * Dm, Wv, Wv_bf, Dm * Dm,
      nullptr, nullptr, 0, nullptr, nullptr, 0, gateA);
  // 3. Q = x @ Wq^T + bq
  gemm_bt_bias<<<dim3(64, 8), 256, 0, stream>>>(
      x_bf, Wq_bf, bq, Qb, Mtok, Dm, Dm, nullptr);
  // 4/5. K, V projections (conditional)
  gemm_bt_bias<<<dim3(64, 8), 256, 0, stream>>>(
      x_bf, Wk_bf, bk, Kb2, Mtok, Dm, Dm, gateA);
  gemm_bt_bias<<<dim3(64, 8), 256, 0, stream>>>(
      x_bf, Wv_bf, bv, Vb2, Mtok, Dm, Dm, gateA);
  // 6. classical softmax attention (conditional)
  attn_classical<<<1024, 256, 0, stream>>>(Qb, Kb2, Vb2, clsb, gateA);
  // 7. quantum transform + gate mix -> bf16
  quantum_mix<<<1024, 256, 0, stream>>>(Qb, theta, gateA, clsb, mix_bf,
                                        Mtok * 64);
  // 8. attn_out = mix @ Wo^T + bo
  gemm_bt_bias<<<dim3(64, 8), 256, 0, stream>>>(
      mix_bf, Wo_bf, bo, attn, Mtok, Dm, Dm, nullptr);
  // 9. x1 = LN(x + attn_out); qm = cos(x1[:, :8]) * cos(phi)
  add_ln<<<4096, 256, 0, stream>>>(x, attn, nullptr, nullptr,
                                   ln1w, ln1b, x1, phi, qmb);
  // 10. hq = relu(qm @ W1^T + b1) (bf16)
  ffn_h<<<4096, 256, 0, stream>>>(qmb, 8, W1, b1, hq_bf, nullptr);
  // 11. hc = relu(x1[:, :8] @ W1^T + b1) (conditional)
  ffn_h<<<4096, 256, 0, stream>>>(x1, 512, W1, b1, hc_bf, gateF);
  // 12. F = hq @ W2^T + b2
  gemm_bt_bias<<<dim3(64, 8), 256, 0, stream>>>(
      hq_bf, W2_bf, b2, Fb, Mtok, Dm, FFn, nullptr);
  // 13. Fc = hc @ W2^T + b2 (conditional)
  gemm_bt_bias<<<dim3(64, 8), 256, 0, stream>>>(
      hc_bf, W2_bf, b2, Fc, Mtok, Dm, FFn, gateF);
  // 14. out = LN(x1 + gF*F + (1-gF)*Fc)
  add_ln<<<4096, 256, 0, stream>>>(x1, Fb, Fc, gateF,
                                   ln2w, ln2b, out, nullptr, nullptr);
}